// Round 13
// baseline (158.506 us; speedup 1.0000x reference)
//
#include <hip/hip_runtime.h>
#include <hip/hip_bf16.h>

typedef __attribute__((ext_vector_type(8))) short short8;
typedef __attribute__((ext_vector_type(4))) float f32x4;
typedef __attribute__((ext_vector_type(16))) float f32x16;

#define LDSTB 514   // bf16 elems per LDS B row (512 + 2 pad) — verified R11 (459K conflicts)
#define LDS_BYTES (128 * LDSTB * 2)   // 131584 B

static __device__ __forceinline__ unsigned short f2bf(float f) {
    union { __hip_bfloat16 h; unsigned short u; } cv;
    cv.h = __float2bfloat16(f);
    return cv.u;
}

// Build Wbig[m=o*8+k][kk=f*8+j] = sum_i C[i,j,k] * W[i,o,f], cast to bf16 (plain layout).
__global__ __launch_bounds__(256) void build_wbig(const float* __restrict__ W,
                                                  unsigned short* __restrict__ Wbig) {
    __shared__ float C[8][8][8];
    const int t = threadIdx.x;
    for (int i = t; i < 512; i += 256) ((float*)C)[i] = 0.0f;
    __syncthreads();
    if (t == 0) {
        C[0][0][0] = 1.0f;
        for (int i = 1; i < 8; ++i) { C[0][i][i] = 1.0f; C[i][0][i] = 1.0f; C[i][i][0] = -1.0f; }
        const int tr[7][3] = {{1,2,3},{1,4,5},{1,7,6},{2,4,6},{2,5,7},{3,4,7},{3,6,5}};
        for (int q = 0; q < 7; ++q) {
            const int a = tr[q][0], b = tr[q][1], c = tr[q][2];
            const int p[3][3] = {{a,b,c},{b,c,a},{c,a,b}};
            for (int u = 0; u < 3; ++u) {
                C[p[u][0]][p[u][1]][p[u][2]] = 1.0f;
                C[p[u][1]][p[u][0]][p[u][2]] = -1.0f;
            }
        }
    }
    __syncthreads();
    const int e = blockIdx.x * 256 + t;     // 0..262143
    const int m = e >> 9, kk = e & 511;
    const int o = m >> 3, k = m & 7, f = kk >> 3, j = kk & 7;
    float s = 0.0f;
#pragma unroll
    for (int i = 0; i < 8; ++i) s += C[i][j][k] * W[i * 4096 + o * 64 + f];
    Wbig[e] = f2bf(s);
}

// Out[65536][512] = X(fp32->bf16) * Wbig^T + bias.
// Barrier-free streaming GEMM (mfma_f32_32x32x16_bf16), R11 structure +
// explicit depth-4 A-prefetch ring (the piece R11 lacked):
//  - Block (1024 thr, 16 waves) owns 128 output cols; whole B panel
//    (128 x 512 bf16 = 128.5 KB) staged to LDS once -> ONE __syncthreads ->
//    waves free-run (no lockstep, no vmcnt drains ever).
//  - A: per wave-job 32 rows; lane's frag = 32 B contiguous fp32, loaded into
//    a 4-deep register ring (slot = s&3, static under full 64-step unroll);
//    compiler-counted vmcnt waits give ~4 steps of latency cover.
//  - Register budget (128 cap, 4 waves/SIMD): acc 64 + ring 32 + bias 4 + ~26.
__global__ __launch_bounds__(1024, 4) void oct_gemm(const float* __restrict__ X,
                                                    const unsigned short* __restrict__ Wbig,
                                                    const float* __restrict__ Bias,
                                                    float* __restrict__ Out) {
    extern __shared__ unsigned short Bs[];   // [128][LDSTB]

    const int d   = blockIdx.x;              // 0..255
    const int xcd = d & 7;
    const int i   = d >> 3;                  // 0..31
    const int rowBlock = xcd * 8 + (i >> 2); // rows [rowBlock*1024, +1024)
    const int cg  = i & 3;                   // cols [cg*128, +128)
    const int colBase = cg * 128;

    const int t    = threadIdx.x;            // 0..1023
    const int lane = t & 63;
    const int w    = t >> 6;                 // wave 0..15
    const int l31  = lane & 31;
    const int l5   = lane >> 5;              // 0..1

    // ---- stage the block's whole B panel to LDS (once; verified R11) ----
    {
        const int r  = t >> 3;               // 0..127
        const int c0 = (t & 7) * 64;         // 0..448
#pragma unroll
        for (int j = 0; j < 8; ++j) {
            short8 v = *reinterpret_cast<const short8*>(
                Wbig + (size_t)(colBase + r) * 512 + c0 + j * 8);
            *reinterpret_cast<short8*>(&Bs[r * LDSTB + c0 + j * 8]) = v;
        }
    }
    __syncthreads();   // the ONLY barrier

    // B frag LDS element offsets per nf: row = nf*32 + l31, k-off = l5*8
    int boff[4];
#pragma unroll
    for (int nf = 0; nf < 4; ++nf)
        boff[nf] = (nf * 32 + l31) * LDSTB + l5 * 8;

    // Bias (4 regs, whole-kernel lifetime)
    float bvv[4];
#pragma unroll
    for (int nf = 0; nf < 4; ++nf) bvv[nf] = Bias[colBase + nf * 32 + l31];

    // Per-job A base pointers (jobs = 2 x 32 rows per wave)
    const float* Ap0 = X + (size_t)(rowBlock * 1024 + (w * 2 + 0) * 32 + l31) * 512 + l5 * 8;
    const float* Ap1 = X + (size_t)(rowBlock * 1024 + (w * 2 + 1) * 32 + l31) * 512 + l5 * 8;

    f32x4 va[4][2];    // depth-4 ring (32 VGPR)

#define AISSUE(SLOT, U) do { \
    const float* _p = (((U) >> 5) ? Ap1 : Ap0) + ((U) & 31) * 16; \
    va[SLOT][0] = *reinterpret_cast<const f32x4*>(_p); \
    va[SLOT][1] = *reinterpret_cast<const f32x4*>(_p + 4); \
    } while (0)

    // Prologue: fill the ring (steps 0..3)
    AISSUE(0, 0); AISSUE(1, 1); AISSUE(2, 2); AISSUE(3, 3);

    f32x16 acc[4];

    // ---- flattened free-running loop: 2 jobs x 32 k-steps, fully unrolled ----
#pragma unroll
    for (int s = 0; s < 64; ++s) {
        if ((s & 31) == 0) {
#pragma unroll
            for (int nf = 0; nf < 4; ++nf)
#pragma unroll
                for (int r = 0; r < 16; ++r) acc[nf][r] = bvv[nf];
        }

        // consume ring slot s&3 (compiler inserts counted vmcnt wait)
        short8 af;
#pragma unroll
        for (int j = 0; j < 8; ++j)
            af[j] = (short)f2bf(va[s & 3][j >> 2][j & 3]);

        // refill the slot with step s+4 (stays in flight across the MFMAs)
        if (s + 4 < 64) AISSUE(s & 3, s + 4);
        __builtin_amdgcn_sched_barrier(0);   // don't sink the refill below MFMAs

#pragma unroll
        for (int nf = 0; nf < 4; ++nf) {
            const short8 bfr = *reinterpret_cast<const short8*>(&Bs[boff[nf] + (s & 31) * 16]);
            acc[nf] = __builtin_amdgcn_mfma_f32_32x32x16_bf16(af, bfr, acc[nf], 0, 0, 0);
        }

        if ((s & 31) == 31) {
            // job epilogue (verified R11): D row = (r&3)+8*(r>>2)+4*l5, col = l&31
            const int row0 = rowBlock * 1024 + (w * 2 + (s >> 5)) * 32;
#pragma unroll
            for (int nf = 0; nf < 4; ++nf) {
                const int col = colBase + nf * 32 + l31;
#pragma unroll
                for (int r = 0; r < 16; ++r) {
                    const int row = row0 + (r & 3) + 8 * (r >> 2) + 4 * l5;
                    Out[(size_t)row * 512 + col] = acc[nf][r];
                }
            }
        }
    }
#undef AISSUE
}

extern "C" void kernel_launch(void* const* d_in, const int* in_sizes, int n_in,
                              void* d_out, int out_size, void* d_ws, size_t ws_size,
                              hipStream_t stream) {
    const float* x = (const float*)d_in[0];   // [65536][512]
    const float* W = (const float*)d_in[1];   // [8][64][64]
    const float* b = (const float*)d_in[2];   // [512]
    float* out = (float*)d_out;               // [65536][512]
    unsigned short* Wbig = (unsigned short*)d_ws;  // 512*512 bf16 = 512 KB

    static bool attr_done = false;
    if (!attr_done) {
        hipFuncSetAttribute((const void*)oct_gemm,
                            hipFuncAttributeMaxDynamicSharedMemorySize, LDS_BYTES);
        attr_done = true;
    }

    build_wbig<<<1024, 256, 0, stream>>>(W, Wbig);
    oct_gemm<<<256, 1024, LDS_BYTES, stream>>>(x, Wbig, b, out);
}

// Round 14
// 91.921 us; speedup vs baseline: 1.7244x; 1.7244x over previous
//
#include <hip/hip_runtime.h>
#include <hip/hip_bf16.h>

typedef __attribute__((ext_vector_type(8))) short short8;
typedef __attribute__((ext_vector_type(4))) float f32x4;
typedef __attribute__((ext_vector_type(16))) float f32x16;

#define LDSTB 514   // bf16 elems per LDS B row (512 + 2 pad) — verified R11 (459K conflicts)
#define LDS_BYTES (128 * LDSTB * 2)   // 131584 B

static __device__ __forceinline__ unsigned short f2bf(float f) {
    union { __hip_bfloat16 h; unsigned short u; } cv;
    cv.h = __float2bfloat16(f);
    return cv.u;
}

// Build Wbig[m=o*8+k][kk=f*8+j] = sum_i C[i,j,k] * W[i,o,f], cast to bf16 (plain layout).
__global__ __launch_bounds__(256) void build_wbig(const float* __restrict__ W,
                                                  unsigned short* __restrict__ Wbig) {
    __shared__ float C[8][8][8];
    const int t = threadIdx.x;
    for (int i = t; i < 512; i += 256) ((float*)C)[i] = 0.0f;
    __syncthreads();
    if (t == 0) {
        C[0][0][0] = 1.0f;
        for (int i = 1; i < 8; ++i) { C[0][i][i] = 1.0f; C[i][0][i] = 1.0f; C[i][i][0] = -1.0f; }
        const int tr[7][3] = {{1,2,3},{1,4,5},{1,7,6},{2,4,6},{2,5,7},{3,4,7},{3,6,5}};
        for (int q = 0; q < 7; ++q) {
            const int a = tr[q][0], b = tr[q][1], c = tr[q][2];
            const int p[3][3] = {{a,b,c},{b,c,a},{c,a,b}};
            for (int u = 0; u < 3; ++u) {
                C[p[u][0]][p[u][1]][p[u][2]] = 1.0f;
                C[p[u][1]][p[u][0]][p[u][2]] = -1.0f;
            }
        }
    }
    __syncthreads();
    const int e = blockIdx.x * 256 + t;     // 0..262143
    const int m = e >> 9, kk = e & 511;
    const int o = m >> 3, k = m & 7, f = kk >> 3, j = kk & 7;
    float s = 0.0f;
#pragma unroll
    for (int i = 0; i < 8; ++i) s += C[i][j][k] * W[i * 4096 + o * 64 + f];
    Wbig[e] = f2bf(s);
}

// Out[65536][512] = X(fp32->bf16) * Wbig^T + bias.
// Barrier-free streaming GEMM (mfma_f32_32x32x16_bf16), 512-thr blocks:
//  - 8 waves/block => 256-reg budget (2 waves/SIMD) -- spill-proof by design.
//  - Block owns 128 cols; whole B panel (128x512 bf16) staged to LDS once ->
//    ONE __syncthreads -> waves free-run. No lockstep, no vmcnt drains.
//  - Wave tile 64 rows x 128 cols (2 row-frags, acc = 8 x f32x16 = 128 regs).
//  - A: depth-4 register ring (4 slots x 16 regs); all k-walk addressing is
//    immediate offsets off 2 base pointers; compiler-counted vmcnt gives
//    ~3 steps of latency cover; ~128 KB/CU in flight.
__global__ __launch_bounds__(512, 2) void oct_gemm(const float* __restrict__ X,
                                                   const unsigned short* __restrict__ Wbig,
                                                   const float* __restrict__ Bias,
                                                   float* __restrict__ Out) {
    extern __shared__ unsigned short Bs[];   // [128][LDSTB]

    const int d   = blockIdx.x;              // 0..255
    const int xcd = d & 7;
    const int i   = d >> 3;                  // 0..31
    const int rowBlock = xcd * 8 + (i >> 2); // rows [rowBlock*1024, +1024)
    const int colBase  = (i & 3) * 128;      // 4 col-group blocks share an XCD

    const int t    = threadIdx.x;            // 0..511
    const int lane = t & 63;
    const int w    = t >> 6;                 // wave 0..7
    const int l31  = lane & 31;
    const int l5   = lane >> 5;              // 0..1

    // ---- stage the block's whole B panel to LDS (once; layout verified R11) ----
    {
        const int r  = t >> 2;               // 0..127
        const int c0 = (t & 3) * 128;        // 0..384
#pragma unroll
        for (int j = 0; j < 16; ++j) {
            short8 v = *reinterpret_cast<const short8*>(
                Wbig + (size_t)(colBase + r) * 512 + c0 + j * 8);
            *reinterpret_cast<short8*>(&Bs[r * LDSTB + c0 + j * 8]) = v;
        }
    }
    __syncthreads();   // the ONLY barrier

    // B frag LDS offsets: row = nf*32 + l31, k-off = l5*8 (+ s*16 via immediate)
    int boff[4];
#pragma unroll
    for (int nf = 0; nf < 4; ++nf)
        boff[nf] = (nf * 32 + l31) * LDSTB + l5 * 8;

    float bvv[4];
#pragma unroll
    for (int nf = 0; nf < 4; ++nf) bvv[nf] = Bias[colBase + nf * 32 + l31];

    f32x4 ring[4][4];   // [slot][frag0.lo, frag0.hi, frag1.lo, frag1.hi] = 64 regs

#pragma unroll
    for (int job = 0; job < 2; ++job) {
        const int rbase = rowBlock * 1024 + job * 512 + w * 64;
        const float* Ap0 = X + (size_t)(rbase + l31) * 512 + l5 * 8;        // rows +0..31
        const float* Ap1 = X + (size_t)(rbase + 32 + l31) * 512 + l5 * 8;   // rows +32..63

#define AISSUE(SLOT, S) do { \
        ring[SLOT][0] = *reinterpret_cast<const f32x4*>(Ap0 + (S) * 16); \
        ring[SLOT][1] = *reinterpret_cast<const f32x4*>(Ap0 + (S) * 16 + 4); \
        ring[SLOT][2] = *reinterpret_cast<const f32x4*>(Ap1 + (S) * 16); \
        ring[SLOT][3] = *reinterpret_cast<const f32x4*>(Ap1 + (S) * 16 + 4); \
    } while (0)

        AISSUE(0, 0); AISSUE(1, 1); AISSUE(2, 2); AISSUE(3, 3);

        f32x16 acc[2][4];
#pragma unroll
        for (int f = 0; f < 2; ++f)
#pragma unroll
            for (int nf = 0; nf < 4; ++nf)
#pragma unroll
                for (int r = 0; r < 16; ++r) acc[f][nf][r] = 0.0f;

        // ---- free-running K loop: 32 steps of K=16, fully unrolled ----
#pragma unroll
        for (int s = 0; s < 32; ++s) {
            // consume ring slot s&3 (compiler inserts counted vmcnt wait)
            short8 af0, af1;
#pragma unroll
            for (int j = 0; j < 8; ++j) {
                af0[j] = (short)f2bf(ring[s & 3][j >> 2][j & 3]);
                af1[j] = (short)f2bf(ring[s & 3][2 + (j >> 2)][j & 3]);
            }
            // refill slot with step s+4 (stays in flight across the MFMAs)
            if (s + 4 < 32) AISSUE(s & 3, s + 4);
            __builtin_amdgcn_sched_barrier(0);

#pragma unroll
            for (int nf = 0; nf < 4; ++nf) {
                const short8 bfr = *reinterpret_cast<const short8*>(&Bs[boff[nf] + s * 16]);
                acc[0][nf] = __builtin_amdgcn_mfma_f32_32x32x16_bf16(af0, bfr, acc[0][nf], 0, 0, 0);
                acc[1][nf] = __builtin_amdgcn_mfma_f32_32x32x16_bf16(af1, bfr, acc[1][nf], 0, 0, 0);
            }
        }
#undef AISSUE

        // ---- epilogue: D row = (r&3)+8*(r>>2)+4*l5, col = l&31 (verified R11) ----
#pragma unroll
        for (int f = 0; f < 2; ++f) {
#pragma unroll
            for (int nf = 0; nf < 4; ++nf) {
                const int col = colBase + nf * 32 + l31;
#pragma unroll
                for (int r = 0; r < 16; ++r) {
                    const int row = rbase + f * 32 + (r & 3) + 8 * (r >> 2) + 4 * l5;
                    Out[(size_t)row * 512 + col] = acc[f][nf][r] + bvv[nf];
                }
            }
        }
    }
}

extern "C" void kernel_launch(void* const* d_in, const int* in_sizes, int n_in,
                              void* d_out, int out_size, void* d_ws, size_t ws_size,
                              hipStream_t stream) {
    const float* x = (const float*)d_in[0];   // [65536][512]
    const float* W = (const float*)d_in[1];   // [8][64][64]
    const float* b = (const float*)d_in[2];   // [512]
    float* out = (float*)d_out;               // [65536][512]
    unsigned short* Wbig = (unsigned short*)d_ws;  // 512*512 bf16 = 512 KB

    static bool attr_done = false;
    if (!attr_done) {
        hipFuncSetAttribute((const void*)oct_gemm,
                            hipFuncAttributeMaxDynamicSharedMemorySize, LDS_BYTES);
        attr_done = true;
    }

    build_wbig<<<1024, 256, 0, stream>>>(W, Wbig);
    oct_gemm<<<256, 512, LDS_BYTES, stream>>>(x, Wbig, b, out);
}

// Round 15
// 72.018 us; speedup vs baseline: 2.2009x; 1.2764x over previous
//
#include <hip/hip_runtime.h>
#include <hip/hip_bf16.h>

typedef __attribute__((ext_vector_type(8))) short short8;
typedef __attribute__((ext_vector_type(4))) float f32x4;
typedef __attribute__((address_space(1))) const unsigned int as1_u32;
typedef __attribute__((address_space(3))) unsigned int as3_u32;

#define BM 128
#define BN 256
#define NH 16                      // K=512 in 16 half-tiles of 32
#define LDS_BYTES (4 * 16384 + 4 * 16384)   // 4 A-halves (fp32) + 4 B-halves (bf16) = 128 KB

static __device__ __forceinline__ unsigned short f2bf(float f) {
    union { __hip_bfloat16 h; unsigned short u; } cv;
    cv.h = __float2bfloat16(f);
    return cv.u;
}

__device__ __forceinline__ void gload16(const void* g, void* l) {
    __builtin_amdgcn_global_load_lds((as1_u32*)g, (as3_u32*)l, 16, 0, 0);
}

// Build WbigS: octonion-folded weight, bf16, PRE-SWIZZLED for the gload stream.
// Logical Wbig[m][kk] = sum_i C[i,j,k]*W[i,o,f]  (m=o*8+k, kk=f*8+j).
// Chunk (nt=m>>8, H=kk>>5) = 16 KB = 8192 elems, loaded linearly to LDS.
// Within chunk: col c=m&255, granule g=(kk>>3)&3 stored at g^((c>>1)&3), elem e=kk&7:
//   idx = ((nt*16+H)<<13) + 32*c + 8*(g ^ ((c>>1)&3)) + e
__global__ __launch_bounds__(256) void build_wbig(const float* __restrict__ W,
                                                  unsigned short* __restrict__ WbigS) {
    __shared__ float C[8][8][8];
    const int t = threadIdx.x;
    for (int i = t; i < 512; i += 256) ((float*)C)[i] = 0.0f;
    __syncthreads();
    if (t == 0) {
        C[0][0][0] = 1.0f;
        for (int i = 1; i < 8; ++i) { C[0][i][i] = 1.0f; C[i][0][i] = 1.0f; C[i][i][0] = -1.0f; }
        const int tr[7][3] = {{1,2,3},{1,4,5},{1,7,6},{2,4,6},{2,5,7},{3,4,7},{3,6,5}};
        for (int q = 0; q < 7; ++q) {
            const int a = tr[q][0], b = tr[q][1], c = tr[q][2];
            const int p[3][3] = {{a,b,c},{b,c,a},{c,a,b}};
            for (int u = 0; u < 3; ++u) {
                C[p[u][0]][p[u][1]][p[u][2]] = 1.0f;
                C[p[u][1]][p[u][0]][p[u][2]] = -1.0f;
            }
        }
    }
    __syncthreads();
    const int e = blockIdx.x * 256 + t;     // 0..262143
    const int m = e >> 9, kk = e & 511;
    const int o = m >> 3, k = m & 7, f = kk >> 3, j = kk & 7;
    float s = 0.0f;
#pragma unroll
    for (int i = 0; i < 8; ++i) s += C[i][j][k] * W[i * 4096 + o * 64 + f];

    const int nt = m >> 8, c = m & 255;
    const int H = kk >> 5, g = (kk >> 3) & 3, e8 = kk & 7;
    const int idx = ((nt * 16 + H) << 13) + 32 * c + 8 * (g ^ ((c >> 1) & 3)) + e8;
    WbigS[idx] = f2bf(s);
}

// Out[65536][512] = X(fp32->bf16 at read) * Wbig^T + bias.
// m201-style pipeline: BOTH operands via global_load_lds (zero staging regs,
// zero ds_writes). 4 half-buffers each; 3 halves (12 vmem instrs) in flight
// continuously; per half: {issue gloads(h+3) | 12 ds_read frags | 16 MFMA |
// vmcnt(8) + raw barrier}. vmcnt counted, never drained until the tail.
// A staged as RAW fp32 (cvt at frag read); A bank-swizzle via per-lane global
// source address (m173); B swizzle baked into WbigS.
__global__ __launch_bounds__(512, 2) void oct_gemm(const float* __restrict__ X,
                                                   const unsigned short* __restrict__ WbigS,
                                                   const float* __restrict__ Bias,
                                                   float* __restrict__ Out) {
    extern __shared__ char smem[];
    float* Ah          = (float*)smem;                       // 4 x [128][32] fp32 (swizzled)
    unsigned short* Bh = (unsigned short*)(smem + 65536);    // 4 x [256][32] bf16 (swizzled)

    // XCD swizzle (1024 % 8 == 0): pair the 2 col-tiles of each row-tile.
    const int bid = blockIdx.x;          // 0..1023
    const int xcd = bid & 7;
    const int idx = bid >> 3;            // 0..127
    const int mtile = xcd * 64 + (idx >> 1);
    const int nt    = idx & 1;
    const int rowBase = mtile * BM;
    const int colBase = nt * BN;

    const int t    = threadIdx.x;        // 0..511
    const int lane = t & 63;
    const int w    = t >> 6;             // 0..7
    const int wr   = w >> 2;             // 0..1  (64-row half)
    const int wc   = w & 3;              // 0..3  (64-col quarter)
    const int l15  = lane & 15;
    const int l4   = lane >> 4;          // 0..3

    // ---- A per-lane global bases: LDS slot s=(j*512+w*64+lane) holds logical
    // piece: r=s>>3, q_log=((s>>1)&3)^(r&3), f0=q_log*8+(s&1)*4  (XOR involution)
    const float* Ag0;
    const float* Ag1;
    {
        int s = w * 64 + lane;
        int r = s >> 3, q = ((s >> 1) & 3) ^ (r & 3);
        Ag0 = X + (size_t)(rowBase + r) * 512 + q * 8 + (s & 1) * 4;
        s += 512;
        r = s >> 3; q = ((s >> 1) & 3) ^ (r & 3);
        Ag1 = X + (size_t)(rowBase + r) * 512 + q * 8 + (s & 1) * 4;
    }
    const unsigned short* Bg0 = WbigS + ((size_t)nt << 17) + ((w * 64 + lane) << 3);
    const unsigned short* Bg1 = Bg0 + (512 << 3);

    // LDS dest offsets (wave-uniform; HW adds lane*16B)
    const int ad0 = w * 256, ad1 = 2048 + w * 256;   // fp32 elems
    const int bd0 = w * 512, bd1 = 4096 + w * 512;   // u16 elems

#define GLOAD(HB, H) do { \
    gload16(Ag0 + (H) * 32, Ah + (HB) * 4096 + ad0); \
    gload16(Ag1 + (H) * 32, Ah + (HB) * 4096 + ad1); \
    gload16(Bg0 + ((H) << 13), Bh + (HB) * 8192 + bd0); \
    gload16(Bg1 + ((H) << 13), Bh + (HB) * 8192 + bd1); \
    } while (0)

    // Frag read offsets. A: row r=wr*64+mi*16+l15, granule at l4^(r&3)=l4^(l15&3).
    // B: col c=wc*64+ni*16+l15, granule at l4^((c>>1)&3)=l4^((l15>>1)&3).
    const int aoff = (wr * 64 + l15) * 32 + (l4 ^ (l15 & 3)) * 8;        // +mi*512
    const int boff = (wc * 64 + l15) * 32 + (l4 ^ ((l15 >> 1) & 3)) * 8; // +ni*512

    // Bias folded into accumulator init (D col = lane&15 for all 4 regs).
    f32x4 acc[4][4];
#pragma unroll
    for (int ni = 0; ni < 4; ++ni) {
        const float bv = Bias[colBase + wc * 64 + ni * 16 + l15];
#pragma unroll
        for (int mi = 0; mi < 4; ++mi) acc[mi][ni] = (f32x4){bv, bv, bv, bv};
    }

#define HALF(HB) do { \
    short8 bf[4]; \
    _Pragma("unroll") \
    for (int ni = 0; ni < 4; ++ni) \
        bf[ni] = *reinterpret_cast<const short8*>(Bh + (HB) * 8192 + boff + ni * 512); \
    __builtin_amdgcn_s_setprio(1); \
    _Pragma("unroll") \
    for (int mi = 0; mi < 4; ++mi) { \
        const f32x4 lo = *reinterpret_cast<const f32x4*>(Ah + (HB) * 4096 + aoff + mi * 512); \
        const f32x4 hi = *reinterpret_cast<const f32x4*>(Ah + (HB) * 4096 + aoff + mi * 512 + 4); \
        short8 af; \
        af[0]=(short)f2bf(lo[0]); af[1]=(short)f2bf(lo[1]); \
        af[2]=(short)f2bf(lo[2]); af[3]=(short)f2bf(lo[3]); \
        af[4]=(short)f2bf(hi[0]); af[5]=(short)f2bf(hi[1]); \
        af[6]=(short)f2bf(hi[2]); af[7]=(short)f2bf(hi[3]); \
        _Pragma("unroll") \
        for (int ni = 0; ni < 4; ++ni) \
            acc[mi][ni] = __builtin_amdgcn_mfma_f32_16x16x32_bf16(af, bf[ni], acc[mi][ni], 0, 0, 0); \
    } \
    __builtin_amdgcn_s_setprio(0); \
    } while (0)

#define ENDBAR(N) do { \
    asm volatile("s_waitcnt vmcnt(" #N ")" ::: "memory"); \
    __builtin_amdgcn_s_barrier(); \
    } while (0)

    // Prologue: halves 0,1,2 in flight (12 instrs); retire half 0; barrier.
    GLOAD(0, 0); GLOAD(1, 1); GLOAD(2, 2);
    ENDBAR(8);

    // Main: h = 0..11 (buffer = h&3, static via 4-unroll). Each line: issue
    // h+3 (its buffer was consumed at h-1, freed by last barrier), compute h,
    // then vmcnt(8) retires h+1 (leaves h+2, h+3 = 8 instrs in flight).
#pragma unroll
    for (int hq = 0; hq < 3; ++hq) {
        GLOAD(3, 4 * hq + 3); HALF(0); ENDBAR(8);
        GLOAD(0, 4 * hq + 4); HALF(1); ENDBAR(8);
        GLOAD(1, 4 * hq + 5); HALF(2); ENDBAR(8);
        GLOAD(2, 4 * hq + 6); HALF(3); ENDBAR(8);
    }
    // Tail: h = 12..15 (last issue is half 15 at h=12).
    GLOAD(3, 15); HALF(0); ENDBAR(8);   // retires 13; 14,15 in flight
    HALF(1); ENDBAR(4);                 // retires 14
    HALF(2); ENDBAR(0);                 // retires 15
    HALF(3);

    // Epilogue: plain fp32 stores (verified clean 131 MB pattern).
#pragma unroll
    for (int mi = 0; mi < 4; ++mi) {
        const int row0 = rowBase + wr * 64 + mi * 16 + l4 * 4;
#pragma unroll
        for (int ni = 0; ni < 4; ++ni) {
            const int col = colBase + wc * 64 + ni * 16 + l15;
#pragma unroll
            for (int r = 0; r < 4; ++r)
                Out[(size_t)(row0 + r) * 512 + col] = acc[mi][ni][r];
        }
    }
#undef GLOAD
#undef HALF
#undef ENDBAR
}

extern "C" void kernel_launch(void* const* d_in, const int* in_sizes, int n_in,
                              void* d_out, int out_size, void* d_ws, size_t ws_size,
                              hipStream_t stream) {
    const float* x = (const float*)d_in[0];   // [65536][512]
    const float* W = (const float*)d_in[1];   // [8][64][64]
    const float* b = (const float*)d_in[2];   // [512]
    float* out = (float*)d_out;               // [65536][512]
    unsigned short* WbigS = (unsigned short*)d_ws;  // 512 KB pre-swizzled stream

    static bool attr_done = false;
    if (!attr_done) {
        hipFuncSetAttribute((const void*)oct_gemm,
                            hipFuncAttributeMaxDynamicSharedMemorySize, LDS_BYTES);
        attr_done = true;
    }

    build_wbig<<<1024, 256, 0, stream>>>(W, WbigS);
    oct_gemm<<<1024, 512, LDS_BYTES, stream>>>(x, WbigS, b, out);
}